// Round 1
// baseline (2143.556 us; speedup 1.0000x reference)
//
#include <hip/hip_runtime.h>

#define N_NODES 50000
#define N_EDGES 800000
#define F 64
#define NROWS (N_NODES * 3)          // 150000 node-(v) rows
#define EROWS (N_EDGES * 3)          // 2400000 edge-(v) rows
#define NPX (N_NODES * 3 * F)        // 9,600,000 floats (px_out size)

// --- tiny 64x64 matmul pair: O = A @ B (row-major), one product per block ---
__global__ __launch_bounds__(256) void mm64_pair(
    const float* __restrict__ A0, const float* __restrict__ B0, float* __restrict__ O0,
    const float* __restrict__ A1, const float* __restrict__ B1, float* __restrict__ O1) {
  const float* A = (blockIdx.x == 0) ? A0 : A1;
  const float* B = (blockIdx.x == 0) ? B0 : B1;
  float* O = (blockIdx.x == 0) ? O0 : O1;
  __shared__ float As[64][65];
  __shared__ float Bs[64][65];
  int t = threadIdx.x;
  for (int k = 0; k < 16; ++k) {
    int idx = t + 256 * k;                    // 0..4095
    As[idx >> 6][idx & 63] = A[idx];
    Bs[idx >> 6][idx & 63] = B[idx];
  }
  __syncthreads();
  int g = t >> 2, f0 = (t & 3) * 16;
  float acc[16];
  #pragma unroll
  for (int j = 0; j < 16; ++j) acc[j] = 0.f;
  for (int k = 0; k < 64; ++k) {
    float a = As[g][k];
    #pragma unroll
    for (int j = 0; j < 16; ++j) acc[j] += a * Bs[k][f0 + j];
  }
  for (int j = 0; j < 16; ++j) O[g * 64 + f0 + j] = acc[j];
}

// --- node GEMM: y_i[r,:] = px[r,:] @ Bi^T ; y_j[r,:] = px[r,:] @ Bj^T ---
// tile: 64 rows x 128 outputs per block; thread = 8 rows x 4 outputs
__global__ __launch_bounds__(256) void node_mm(
    const float* __restrict__ px, const float* __restrict__ Bi,
    const float* __restrict__ Bj, float* __restrict__ yi, float* __restrict__ yj) {
  __shared__ float pxs[64][68];    // padded to 272B rows (16B aligned)
  __shared__ float Bs[128][68];    // rows 0..63 = Bi, 64..127 = Bj  (B[g][f])
  int t = threadIdx.x;
  int r0 = blockIdx.x * 64;
  #pragma unroll
  for (int k = 0; k < 8; ++k) {
    int idx = t + 256 * k;                    // 0..2047 float4s
    int row = idx >> 4, c4 = (idx & 15) * 4;
    const float* src = (row < 64) ? (Bi + row * 64 + c4) : (Bj + (row - 64) * 64 + c4);
    *(float4*)&Bs[row][c4] = *(const float4*)src;
  }
  #pragma unroll
  for (int k = 0; k < 4; ++k) {
    int idx = t + 256 * k;                    // 0..1023 float4s
    int lr = idx >> 4, c4 = (idx & 15) * 4;
    float4 v = make_float4(0.f, 0.f, 0.f, 0.f);
    if (r0 + lr < NROWS) v = *(const float4*)(px + (size_t)(r0 + lr) * 64 + c4);
    *(float4*)&pxs[lr][c4] = v;
  }
  __syncthreads();
  int q = t & 31;          // output quad: g = 4q .. 4q+3 (0..127)
  int rg = t >> 5;         // row group: rows rg*8 .. rg*8+7
  float acc[8][4];
  #pragma unroll
  for (int r = 0; r < 8; ++r)
    #pragma unroll
    for (int j = 0; j < 4; ++j) acc[r][j] = 0.f;
  #pragma unroll 4
  for (int fc = 0; fc < 16; ++fc) {
    float4 b[4];
    #pragma unroll
    for (int j = 0; j < 4; ++j) b[j] = *(const float4*)&Bs[4 * q + j][fc * 4];
    #pragma unroll
    for (int r = 0; r < 8; ++r) {
      float4 p = *(const float4*)&pxs[rg * 8 + r][fc * 4];
      #pragma unroll
      for (int j = 0; j < 4; ++j)
        acc[r][j] += p.x * b[j].x + p.y * b[j].y + p.z * b[j].z + p.w * b[j].w;
    }
  }
  #pragma unroll
  for (int r = 0; r < 8; ++r) {
    int grow = r0 + rg * 8 + r;
    if (grow >= NROWS) continue;
    float4 v = make_float4(acc[r][0], acc[r][1], acc[r][2], acc[r][3]);
    if (q < 16) *(float4*)(yi + (size_t)grow * 64 + q * 4) = v;
    else        *(float4*)(yj + (size_t)grow * 64 + (q - 16) * 4) = v;
  }
}

// --- edge pass: gather y, scale by diff, write ix, atomic-scatter to px_out ---
__global__ __launch_bounds__(256) void edge_kernel(
    const int* __restrict__ idx_i, const int* __restrict__ idx_j,
    const float* __restrict__ diff, const float* __restrict__ yi,
    const float* __restrict__ yj, float* __restrict__ ix_out,
    float* __restrict__ px_out) {
  int t = threadIdx.x;
  int row = blockIdx.x * 16 + (t >> 4);       // (e,v) row, 0..EROWS-1 (exact fit)
  int e = row / 3;
  int v = row - e * 3;
  int ni = idx_i[e];
  int nj = idx_j[e];
  float d = diff[row];
  int c = (t & 15) * 4;
  const float4 a = *(const float4*)(yi + ((size_t)ni * 3 + v) * 64 + c);
  const float4 b = *(const float4*)(yj + ((size_t)nj * 3 + v) * 64 + c);
  float4 r = make_float4(d * (a.x + b.x), d * (a.y + b.y),
                         d * (a.z + b.z), d * (a.w + b.w));
  *(float4*)(ix_out + (size_t)row * 64 + c) = r;
  float* p = px_out + ((size_t)ni * 3 + v) * 64 + c;
  atomicAdd(p + 0, r.x);
  atomicAdd(p + 1, r.y);
  atomicAdd(p + 2, r.z);
  atomicAdd(p + 3, r.w);
}

extern "C" void kernel_launch(void* const* d_in, const int* in_sizes, int n_in,
                              void* d_out, int out_size, void* d_ws, size_t ws_size,
                              hipStream_t stream) {
  const int*   idx_i = (const int*)d_in[0];
  const int*   idx_j = (const int*)d_in[1];
  const float* px    = (const float*)d_in[2];
  const float* diff  = (const float*)d_in[3];
  const float* W_pp  = (const float*)d_in[4];
  const float* W_i   = (const float*)d_in[5];
  const float* W_j   = (const float*)d_in[6];
  const float* W_ii  = (const float*)d_in[7];

  float* px_out = (float*)d_out;              // [50000,3,64]
  float* ix_out = (float*)d_out + NPX;        // [800000,3,64]

  float* ws = (float*)d_ws;
  float* yi = ws;                              // [150000,64]
  float* yj = ws + (size_t)NPX;                // [150000,64]
  float* Ci = ws + 2 * (size_t)NPX;
  float* Cj = Ci + 4096;
  float* Bi = Cj + 4096;
  float* Bj = Bi + 4096;

  // px_out must be zeroed every call (atomic accumulation target)
  hipMemsetAsync(px_out, 0, (size_t)NPX * sizeof(float), stream);

  // Ci = W_ii @ W_i ; Cj = W_ii @ W_j
  mm64_pair<<<2, 256, 0, stream>>>(W_ii, W_i, Ci, W_ii, W_j, Cj);
  // Bi = Ci @ W_pp ; Bj = Cj @ W_pp   (so Bi = W_ii W_i W_pp)
  mm64_pair<<<2, 256, 0, stream>>>(Ci, W_pp, Bi, Cj, W_pp, Bj);

  node_mm<<<(NROWS + 63) / 64, 256, 0, stream>>>(px, Bi, Bj, yi, yj);

  edge_kernel<<<EROWS / 16, 256, 0, stream>>>(idx_i, idx_j, diff, yi, yj,
                                              ix_out, px_out);
}

// Round 2
// 463.865 us; speedup vs baseline: 4.6211x; 4.6211x over previous
//
#include <hip/hip_runtime.h>

#define N_NODES 50000
#define N_EDGES 800000
#define F 64
#define NROWS (N_NODES * 3)          // 150000 node-(v) rows
#define NPX (N_NODES * 3 * F)        // 9,600,000 floats (px_out size)

// --- tiny 64x64 matmul pair: O = A @ B (row-major), one product per block ---
__global__ __launch_bounds__(256) void mm64_pair(
    const float* __restrict__ A0, const float* __restrict__ B0, float* __restrict__ O0,
    const float* __restrict__ A1, const float* __restrict__ B1, float* __restrict__ O1) {
  const float* A = (blockIdx.x == 0) ? A0 : A1;
  const float* B = (blockIdx.x == 0) ? B0 : B1;
  float* O = (blockIdx.x == 0) ? O0 : O1;
  __shared__ float As[64][65];
  __shared__ float Bs[64][65];
  int t = threadIdx.x;
  for (int k = 0; k < 16; ++k) {
    int idx = t + 256 * k;
    As[idx >> 6][idx & 63] = A[idx];
    Bs[idx >> 6][idx & 63] = B[idx];
  }
  __syncthreads();
  int g = t >> 2, f0 = (t & 3) * 16;
  float acc[16];
  #pragma unroll
  for (int j = 0; j < 16; ++j) acc[j] = 0.f;
  for (int k = 0; k < 64; ++k) {
    float a = As[g][k];
    #pragma unroll
    for (int j = 0; j < 16; ++j) acc[j] += a * Bs[k][f0 + j];
  }
  for (int j = 0; j < 16; ++j) O[g * 64 + f0 + j] = acc[j];
}

// --- node GEMM: y_i[r,:] = px[r,:] @ Bi^T ; y_j[r,:] = px[r,:] @ Bj^T ---
__global__ __launch_bounds__(256) void node_mm(
    const float* __restrict__ px, const float* __restrict__ Bi,
    const float* __restrict__ Bj, float* __restrict__ yi, float* __restrict__ yj) {
  __shared__ float pxs[64][68];
  __shared__ float Bs[128][68];    // rows 0..63 = Bi, 64..127 = Bj
  int t = threadIdx.x;
  int r0 = blockIdx.x * 64;
  #pragma unroll
  for (int k = 0; k < 8; ++k) {
    int idx = t + 256 * k;
    int row = idx >> 4, c4 = (idx & 15) * 4;
    const float* src = (row < 64) ? (Bi + row * 64 + c4) : (Bj + (row - 64) * 64 + c4);
    *(float4*)&Bs[row][c4] = *(const float4*)src;
  }
  #pragma unroll
  for (int k = 0; k < 4; ++k) {
    int idx = t + 256 * k;
    int lr = idx >> 4, c4 = (idx & 15) * 4;
    float4 v = make_float4(0.f, 0.f, 0.f, 0.f);
    if (r0 + lr < NROWS) v = *(const float4*)(px + (size_t)(r0 + lr) * 64 + c4);
    *(float4*)&pxs[lr][c4] = v;
  }
  __syncthreads();
  int q = t & 31;
  int rg = t >> 5;
  float acc[8][4];
  #pragma unroll
  for (int r = 0; r < 8; ++r)
    #pragma unroll
    for (int j = 0; j < 4; ++j) acc[r][j] = 0.f;
  #pragma unroll 4
  for (int fc = 0; fc < 16; ++fc) {
    float4 b[4];
    #pragma unroll
    for (int j = 0; j < 4; ++j) b[j] = *(const float4*)&Bs[4 * q + j][fc * 4];
    #pragma unroll
    for (int r = 0; r < 8; ++r) {
      float4 p = *(const float4*)&pxs[rg * 8 + r][fc * 4];
      #pragma unroll
      for (int j = 0; j < 4; ++j)
        acc[r][j] += p.x * b[j].x + p.y * b[j].y + p.z * b[j].z + p.w * b[j].w;
    }
  }
  #pragma unroll
  for (int r = 0; r < 8; ++r) {
    int grow = r0 + rg * 8 + r;
    if (grow >= NROWS) continue;
    float4 v = make_float4(acc[r][0], acc[r][1], acc[r][2], acc[r][3]);
    if (q < 16) *(float4*)(yi + (size_t)grow * 64 + q * 4) = v;
    else        *(float4*)(yj + (size_t)grow * 64 + (q - 16) * 4) = v;
  }
}

// --- CSR build step 1: histogram of idx_i ---
__global__ __launch_bounds__(256) void hist_kernel(
    const int* __restrict__ idx_i, int* __restrict__ cnt) {
  int e = blockIdx.x * 256 + threadIdx.x;
  if (e < N_EDGES) atomicAdd(&cnt[idx_i[e]], 1);
}

// --- CSR build step 2: exclusive scan (single block, wave-shuffle scan) ---
__global__ __launch_bounds__(1024) void scan_kernel(
    const int* __restrict__ cnt, int* __restrict__ offs, int* __restrict__ cursor) {
  __shared__ int wsum[16];
  __shared__ int carry_s;
  int t = threadIdx.x, w = t >> 6, l = t & 63;
  if (t == 0) { carry_s = 0; offs[0] = 0; }
  __syncthreads();
  for (int base = 0; base < N_NODES; base += 1024) {
    int i = base + t;
    int x = (i < N_NODES) ? cnt[i] : 0;
    int incl = x;
    #pragma unroll
    for (int off = 1; off < 64; off <<= 1) {
      int y = __shfl_up(incl, off, 64);
      if (l >= off) incl += y;
    }
    if (l == 63) wsum[w] = incl;
    __syncthreads();
    if (w == 0 && l < 16) {
      int ws_ = wsum[l];
      int sincl = ws_;
      #pragma unroll
      for (int off = 1; off < 16; off <<= 1) {
        int y = __shfl_up(sincl, off, 64);
        if (l >= off) sincl += y;
      }
      wsum[l] = sincl - ws_;   // exclusive wave base
    }
    __syncthreads();
    int incl_total = incl + wsum[w] + carry_s;
    if (i < N_NODES) {
      offs[i + 1] = incl_total;
      cursor[i] = incl_total - x;
    }
    __syncthreads();
    if (t == 1023) carry_s = incl_total;
    __syncthreads();
  }
}

// --- CSR build step 3: scatter edge ids into node-sorted order ---
__global__ __launch_bounds__(256) void scatter_kernel(
    const int* __restrict__ idx_i, int* __restrict__ cursor, int* __restrict__ perm) {
  int e = blockIdx.x * 256 + threadIdx.x;
  if (e < N_EDGES) {
    int pos = atomicAdd(&cursor[idx_i[e]], 1);
    perm[pos] = e;
  }
}

// --- main: per (node,v) wave — gather yj, write ix, reduce px_out in regs ---
__global__ __launch_bounds__(192) void node_edge_kernel(
    const int* __restrict__ offs, const int* __restrict__ perm,
    const int* __restrict__ idx_j, const float* __restrict__ diff,
    const float* __restrict__ yi, const float* __restrict__ yj,
    float* __restrict__ ix_out, float* __restrict__ px_out) {
  int n = blockIdx.x;
  int v = threadIdx.x >> 6;          // 0..2
  int lane = threadIdx.x & 63;
  int s = lane >> 4;                 // edge slot 0..3
  int fq = (lane & 15) * 4;          // feature quad
  int start = offs[n], end = offs[n + 1];
  const float4 yiv = *(const float4*)(yi + ((size_t)n * 3 + v) * 64 + fq);
  float4 acc = make_float4(0.f, 0.f, 0.f, 0.f);
  float sum_d = 0.f;
  for (int p = start; p < end; p += 4) {
    int pe = p + s;
    int pc = (pe < end) ? pe : (end - 1);   // loop entered => end > start
    int e = perm[pc];
    int nj = idx_j[e];
    float d = (pe < end) ? diff[e * 3 + v] : 0.f;
    const float4 yjv = *(const float4*)(yj + ((size_t)nj * 3 + v) * 64 + fq);
    float4 r = make_float4(d * (yiv.x + yjv.x), d * (yiv.y + yjv.y),
                           d * (yiv.z + yjv.z), d * (yiv.w + yjv.w));
    if (pe < end)
      *(float4*)(ix_out + ((size_t)e * 3 + v) * 64 + fq) = r;
    acc.x += d * yjv.x; acc.y += d * yjv.y;
    acc.z += d * yjv.z; acc.w += d * yjv.w;
    sum_d += d;
  }
  // reduce over the 4 edge slots (lanes xor 16, 32)
  #pragma unroll
  for (int m = 16; m < 64; m <<= 1) {
    acc.x += __shfl_xor(acc.x, m, 64);
    acc.y += __shfl_xor(acc.y, m, 64);
    acc.z += __shfl_xor(acc.z, m, 64);
    acc.w += __shfl_xor(acc.w, m, 64);
    sum_d += __shfl_xor(sum_d, m, 64);
  }
  if (s == 0) {
    float4 o = make_float4(yiv.x * sum_d + acc.x, yiv.y * sum_d + acc.y,
                           yiv.z * sum_d + acc.z, yiv.w * sum_d + acc.w);
    *(float4*)(px_out + ((size_t)n * 3 + v) * 64 + fq) = o;
  }
}

extern "C" void kernel_launch(void* const* d_in, const int* in_sizes, int n_in,
                              void* d_out, int out_size, void* d_ws, size_t ws_size,
                              hipStream_t stream) {
  const int*   idx_i = (const int*)d_in[0];
  const int*   idx_j = (const int*)d_in[1];
  const float* px    = (const float*)d_in[2];
  const float* diff  = (const float*)d_in[3];
  const float* W_pp  = (const float*)d_in[4];
  const float* W_i   = (const float*)d_in[5];
  const float* W_j   = (const float*)d_in[6];
  const float* W_ii  = (const float*)d_in[7];

  float* px_out = (float*)d_out;              // [50000,3,64]
  float* ix_out = (float*)d_out + NPX;        // [800000,3,64]

  float* ws = (float*)d_ws;
  float* yi = ws;                              // [150000,64]
  float* yj = yi + (size_t)NPX;                // [150000,64]
  float* Ci = yj + (size_t)NPX;
  float* Cj = Ci + 4096;
  float* Bi = Cj + 4096;
  float* Bj = Bi + 4096;
  int* cnt    = (int*)(Bj + 4096);             // [50000]
  int* offs   = cnt + N_NODES;                 // [50001]
  int* cursor = offs + N_NODES + 1;            // [50000]
  int* perm   = cursor + N_NODES;              // [800000]

  hipMemsetAsync(cnt, 0, N_NODES * sizeof(int), stream);

  // Bi = W_ii @ W_i @ W_pp ; Bj = W_ii @ W_j @ W_pp
  mm64_pair<<<2, 256, 0, stream>>>(W_ii, W_i, Ci, W_ii, W_j, Cj);
  mm64_pair<<<2, 256, 0, stream>>>(Ci, W_pp, Bi, Cj, W_pp, Bj);

  node_mm<<<(NROWS + 63) / 64, 256, 0, stream>>>(px, Bi, Bj, yi, yj);

  hist_kernel<<<(N_EDGES + 255) / 256, 256, 0, stream>>>(idx_i, cnt);
  scan_kernel<<<1, 1024, 0, stream>>>(cnt, offs, cursor);
  scatter_kernel<<<(N_EDGES + 255) / 256, 256, 0, stream>>>(idx_i, cursor, perm);

  node_edge_kernel<<<N_NODES, 192, 0, stream>>>(offs, perm, idx_j, diff,
                                                yi, yj, ix_out, px_out);
}

// Round 4
// 394.179 us; speedup vs baseline: 5.4380x; 1.1768x over previous
//
#include <hip/hip_runtime.h>

#define N_NODES 50000
#define N_EDGES 800000
#define F 64
#define NROWS (N_NODES * 3)          // 150000 node-(v) rows
#define NPX (N_NODES * 3 * F)        // 9,600,000 floats (px_out size)

typedef float floatx4 __attribute__((ext_vector_type(4)));

// --- tiny 64x64 matmul pair: O = A @ B (row-major), one product per block ---
__global__ __launch_bounds__(256) void mm64_pair(
    const float* __restrict__ A0, const float* __restrict__ B0, float* __restrict__ O0,
    const float* __restrict__ A1, const float* __restrict__ B1, float* __restrict__ O1) {
  const float* A = (blockIdx.x == 0) ? A0 : A1;
  const float* B = (blockIdx.x == 0) ? B0 : B1;
  float* O = (blockIdx.x == 0) ? O0 : O1;
  __shared__ float As[64][65];
  __shared__ float Bs[64][65];
  int t = threadIdx.x;
  for (int k = 0; k < 16; ++k) {
    int idx = t + 256 * k;
    As[idx >> 6][idx & 63] = A[idx];
    Bs[idx >> 6][idx & 63] = B[idx];
  }
  __syncthreads();
  int g = t >> 2, f0 = (t & 3) * 16;
  float acc[16];
  #pragma unroll
  for (int j = 0; j < 16; ++j) acc[j] = 0.f;
  for (int k = 0; k < 64; ++k) {
    float a = As[g][k];
    #pragma unroll
    for (int j = 0; j < 16; ++j) acc[j] += a * Bs[k][f0 + j];
  }
  for (int j = 0; j < 16; ++j) O[g * 64 + f0 + j] = acc[j];
}

// --- node GEMM: y_i[r,:] = px[r,:] @ Bi^T ; y_j[r,:] = px[r,:] @ Bj^T ---
__global__ __launch_bounds__(256) void node_mm(
    const float* __restrict__ px, const float* __restrict__ Bi,
    const float* __restrict__ Bj, float* __restrict__ yi, float* __restrict__ yj) {
  __shared__ float pxs[64][68];
  __shared__ float Bs[128][68];    // rows 0..63 = Bi, 64..127 = Bj
  int t = threadIdx.x;
  int r0 = blockIdx.x * 64;
  #pragma unroll
  for (int k = 0; k < 8; ++k) {
    int idx = t + 256 * k;
    int row = idx >> 4, c4 = (idx & 15) * 4;
    const float* src = (row < 64) ? (Bi + row * 64 + c4) : (Bj + (row - 64) * 64 + c4);
    *(float4*)&Bs[row][c4] = *(const float4*)src;
  }
  #pragma unroll
  for (int k = 0; k < 4; ++k) {
    int idx = t + 256 * k;
    int lr = idx >> 4, c4 = (idx & 15) * 4;
    float4 v = make_float4(0.f, 0.f, 0.f, 0.f);
    if (r0 + lr < NROWS) v = *(const float4*)(px + (size_t)(r0 + lr) * 64 + c4);
    *(float4*)&pxs[lr][c4] = v;
  }
  __syncthreads();
  int q = t & 31;
  int rg = t >> 5;
  float acc[8][4];
  #pragma unroll
  for (int r = 0; r < 8; ++r)
    #pragma unroll
    for (int j = 0; j < 4; ++j) acc[r][j] = 0.f;
  #pragma unroll 4
  for (int fc = 0; fc < 16; ++fc) {
    float4 b[4];
    #pragma unroll
    for (int j = 0; j < 4; ++j) b[j] = *(const float4*)&Bs[4 * q + j][fc * 4];
    #pragma unroll
    for (int r = 0; r < 8; ++r) {
      float4 p = *(const float4*)&pxs[rg * 8 + r][fc * 4];
      #pragma unroll
      for (int j = 0; j < 4; ++j)
        acc[r][j] += p.x * b[j].x + p.y * b[j].y + p.z * b[j].z + p.w * b[j].w;
    }
  }
  #pragma unroll
  for (int r = 0; r < 8; ++r) {
    int grow = r0 + rg * 8 + r;
    if (grow >= NROWS) continue;
    float4 v = make_float4(acc[r][0], acc[r][1], acc[r][2], acc[r][3]);
    if (q < 16) *(float4*)(yi + (size_t)grow * 64 + q * 4) = v;
    else        *(float4*)(yj + (size_t)grow * 64 + (q - 16) * 4) = v;
  }
}

// --- CSR build step 1: histogram of idx_i ---
__global__ __launch_bounds__(256) void hist_kernel(
    const int* __restrict__ idx_i, int* __restrict__ cnt) {
  int e = blockIdx.x * 256 + threadIdx.x;
  if (e < N_EDGES) atomicAdd(&cnt[idx_i[e]], 1);
}

// --- CSR build step 2: exclusive scan, 8 elems/thread (single block) ---
__global__ __launch_bounds__(1024) void scan_kernel(
    const int* __restrict__ cnt, int* __restrict__ offs, int* __restrict__ cursor) {
  __shared__ int wsum[16];
  __shared__ int s_carry;
  int t = threadIdx.x, w = t >> 6, l = t & 63;
  if (t == 0) { s_carry = 0; offs[0] = 0; }
  __syncthreads();
  for (int base = 0; base < N_NODES; base += 8192) {
    int i0 = base + t * 8;
    int x[8];
    if (i0 + 7 < N_NODES) {
      int4 a = *(const int4*)(cnt + i0);
      int4 b = *(const int4*)(cnt + i0 + 4);
      x[0] = a.x; x[1] = a.y; x[2] = a.z; x[3] = a.w;
      x[4] = b.x; x[5] = b.y; x[6] = b.z; x[7] = b.w;
    } else {
      #pragma unroll
      for (int k = 0; k < 8; ++k) x[k] = (i0 + k < N_NODES) ? cnt[i0 + k] : 0;
    }
    int incl[8];
    int p = 0;
    #pragma unroll
    for (int k = 0; k < 8; ++k) { p += x[k]; incl[k] = p; }
    int tsum = p;
    int ts = tsum;
    #pragma unroll
    for (int off = 1; off < 64; off <<= 1) {
      int y = __shfl_up(ts, off, 64);
      if (l >= off) ts += y;
    }
    if (l == 63) wsum[w] = ts;
    __syncthreads();
    if (t < 16) {
      int ws_ = wsum[t];
      int si = ws_;
      #pragma unroll
      for (int off = 1; off < 16; off <<= 1) {
        int y = __shfl_up(si, off, 16);
        if (t >= off) si += y;
      }
      wsum[t] = si - ws_;          // exclusive wave base
    }
    __syncthreads();
    int basev = s_carry + wsum[w] + (ts - tsum);   // exclusive base for this thread
    #pragma unroll
    for (int k = 0; k < 8; ++k) {
      int i = i0 + k;
      if (i < N_NODES) {
        int it = basev + incl[k];
        offs[i + 1] = it;
        cursor[i] = it - x[k];
      }
    }
    __syncthreads();
    if (t == 1023) s_carry = basev + tsum;         // chunk total carried forward
    __syncthreads();
  }
}

// --- CSR build step 3: scatter edge ids into node-sorted order ---
__global__ __launch_bounds__(256) void scatter_kernel(
    const int* __restrict__ idx_i, int* __restrict__ cursor, int* __restrict__ perm) {
  int e = blockIdx.x * 256 + threadIdx.x;
  if (e < N_EDGES) {
    int pos = atomicAdd(&cursor[idx_i[e]], 1);
    perm[pos] = e;
  }
}

// --- main: per (node,v) wave — register-staged edge resolve, then compute ---
__global__ __launch_bounds__(192) void node_edge_kernel(
    const int* __restrict__ offs, const int* __restrict__ perm,
    const int* __restrict__ idx_j, const float* __restrict__ diff,
    const float* __restrict__ yi, const float* __restrict__ yj,
    float* __restrict__ ix_out, float* __restrict__ px_out) {
  int n = blockIdx.x;
  int v = threadIdx.x >> 6;          // 0..2 (one wave per v)
  int lane = threadIdx.x & 63;
  int s = lane >> 4;                 // edge slot 0..3
  int fq = (lane & 15) * 4;          // feature quad
  int start = offs[n], end = offs[n + 1];
  const float4 yiv = *(const float4*)(yi + ((size_t)n * 3 + v) * 64 + fq);
  float4 acc = make_float4(0.f, 0.f, 0.f, 0.f);
  float sum_d = 0.f;

  for (int base = start; base < end; base += 64) {
    int m = end - base; if (m > 64) m = 64;
    // resolve up to 64 edges in parallel (2-deep chain, 64-wide)
    int e = -1, nj = 0; float d = 0.f;
    if (lane < m) {
      e = perm[base + lane];
      nj = idx_j[e];
      d = diff[e * 3 + v];
    }
    // compute: 4 edges in flight per iteration
    for (int c0 = 0; c0 < m; c0 += 4) {
      int c = c0 + s;
      int ec   = __shfl(e, c, 64);
      int njc  = __shfl(nj, c, 64);
      float dc = __shfl(d, c, 64);   // 0 when c >= m
      const float4 yjv = *(const float4*)(yj + ((size_t)njc * 3 + v) * 64 + fq);
      acc.x += dc * yjv.x; acc.y += dc * yjv.y;
      acc.z += dc * yjv.z; acc.w += dc * yjv.w;
      sum_d += dc;
      if (c < m) {
        floatx4 r;
        r.x = dc * (yiv.x + yjv.x); r.y = dc * (yiv.y + yjv.y);
        r.z = dc * (yiv.z + yjv.z); r.w = dc * (yiv.w + yjv.w);
        __builtin_nontemporal_store(r, (floatx4*)(ix_out + ((size_t)ec * 3 + v) * 64 + fq));
      }
    }
  }
  // reduce over the 4 edge slots (lanes xor 16, 32)
  #pragma unroll
  for (int mm = 16; mm < 64; mm <<= 1) {
    acc.x += __shfl_xor(acc.x, mm, 64);
    acc.y += __shfl_xor(acc.y, mm, 64);
    acc.z += __shfl_xor(acc.z, mm, 64);
    acc.w += __shfl_xor(acc.w, mm, 64);
    sum_d += __shfl_xor(sum_d, mm, 64);
  }
  if (s == 0) {
    float4 o = make_float4(yiv.x * sum_d + acc.x, yiv.y * sum_d + acc.y,
                           yiv.z * sum_d + acc.z, yiv.w * sum_d + acc.w);
    *(float4*)(px_out + ((size_t)n * 3 + v) * 64 + fq) = o;
  }
}

extern "C" void kernel_launch(void* const* d_in, const int* in_sizes, int n_in,
                              void* d_out, int out_size, void* d_ws, size_t ws_size,
                              hipStream_t stream) {
  const int*   idx_i = (const int*)d_in[0];
  const int*   idx_j = (const int*)d_in[1];
  const float* px    = (const float*)d_in[2];
  const float* diff  = (const float*)d_in[3];
  const float* W_pp  = (const float*)d_in[4];
  const float* W_i   = (const float*)d_in[5];
  const float* W_j   = (const float*)d_in[6];
  const float* W_ii  = (const float*)d_in[7];

  float* px_out = (float*)d_out;              // [50000,3,64]
  float* ix_out = (float*)d_out + NPX;        // [800000,3,64]

  float* ws = (float*)d_ws;
  float* yi = ws;                              // [150000,64]
  float* yj = yi + (size_t)NPX;                // [150000,64]
  float* Ci = yj + (size_t)NPX;
  float* Cj = Ci + 4096;
  float* Bi = Cj + 4096;
  float* Bj = Bi + 4096;
  int* cnt    = (int*)(Bj + 4096);             // [50000]
  int* offs   = cnt + N_NODES;                 // [50001]
  int* cursor = offs + N_NODES + 1;            // [50000]
  int* perm   = cursor + N_NODES;              // [800000]

  (void)hipMemsetAsync(cnt, 0, N_NODES * sizeof(int), stream);

  // Bi = W_ii @ W_i @ W_pp ; Bj = W_ii @ W_j @ W_pp
  mm64_pair<<<2, 256, 0, stream>>>(W_ii, W_i, Ci, W_ii, W_j, Cj);
  mm64_pair<<<2, 256, 0, stream>>>(Ci, W_pp, Bi, Cj, W_pp, Bj);

  node_mm<<<(NROWS + 63) / 64, 256, 0, stream>>>(px, Bi, Bj, yi, yj);

  hist_kernel<<<(N_EDGES + 255) / 256, 256, 0, stream>>>(idx_i, cnt);
  scan_kernel<<<1, 1024, 0, stream>>>(cnt, offs, cursor);
  scatter_kernel<<<(N_EDGES + 255) / 256, 256, 0, stream>>>(idx_i, cursor, perm);

  node_edge_kernel<<<N_NODES, 192, 0, stream>>>(offs, perm, idx_j, diff,
                                                yi, yj, ix_out, px_out);
}

// Round 5
// 320.659 us; speedup vs baseline: 6.6848x; 1.2293x over previous
//
#include <hip/hip_runtime.h>

#define N_NODES 50000
#define N_EDGES 800000
#define F 64
#define NROWS (N_NODES * 3)          // 150000 node-(v) rows
#define NPX (N_NODES * 3 * F)        // 9,600,000 floats (px_out size)

typedef float floatx4 __attribute__((ext_vector_type(4)));

__device__ __forceinline__ unsigned short f2bf(float f) {
  unsigned int u = __float_as_uint(f);
  return (unsigned short)((u + 0x7FFFu + ((u >> 16) & 1u)) >> 16);
}
__device__ __forceinline__ float bf2f(unsigned short h) {
  return __uint_as_float(((unsigned int)h) << 16);
}

// --- tiny 64x64 matmul pair: O = A @ B (row-major), one product per block ---
__global__ __launch_bounds__(256) void mm64_pair(
    const float* __restrict__ A0, const float* __restrict__ B0, float* __restrict__ O0,
    const float* __restrict__ A1, const float* __restrict__ B1, float* __restrict__ O1) {
  const float* A = (blockIdx.x == 0) ? A0 : A1;
  const float* B = (blockIdx.x == 0) ? B0 : B1;
  float* O = (blockIdx.x == 0) ? O0 : O1;
  __shared__ float As[64][65];
  __shared__ float Bs[64][65];
  int t = threadIdx.x;
  for (int k = 0; k < 16; ++k) {
    int idx = t + 256 * k;
    As[idx >> 6][idx & 63] = A[idx];
    Bs[idx >> 6][idx & 63] = B[idx];
  }
  __syncthreads();
  int g = t >> 2, f0 = (t & 3) * 16;
  float acc[16];
  #pragma unroll
  for (int j = 0; j < 16; ++j) acc[j] = 0.f;
  for (int k = 0; k < 64; ++k) {
    float a = As[g][k];
    #pragma unroll
    for (int j = 0; j < 16; ++j) acc[j] += a * Bs[k][f0 + j];
  }
  for (int j = 0; j < 16; ++j) O[g * 64 + f0 + j] = acc[j];
}

// --- node GEMM: yi[r,:] = px@Bi^T (f32) ; yjb[r,:] = px@Bj^T (bf16) ---
__global__ __launch_bounds__(256) void node_mm(
    const float* __restrict__ px, const float* __restrict__ Bi,
    const float* __restrict__ Bj, float* __restrict__ yi,
    unsigned short* __restrict__ yjb) {
  __shared__ float pxs[64][68];
  __shared__ float Bs[128][68];    // rows 0..63 = Bi, 64..127 = Bj
  int t = threadIdx.x;
  int r0 = blockIdx.x * 64;
  #pragma unroll
  for (int k = 0; k < 8; ++k) {
    int idx = t + 256 * k;
    int row = idx >> 4, c4 = (idx & 15) * 4;
    const float* src = (row < 64) ? (Bi + row * 64 + c4) : (Bj + (row - 64) * 64 + c4);
    *(float4*)&Bs[row][c4] = *(const float4*)src;
  }
  #pragma unroll
  for (int k = 0; k < 4; ++k) {
    int idx = t + 256 * k;
    int lr = idx >> 4, c4 = (idx & 15) * 4;
    float4 v = make_float4(0.f, 0.f, 0.f, 0.f);
    if (r0 + lr < NROWS) v = *(const float4*)(px + (size_t)(r0 + lr) * 64 + c4);
    *(float4*)&pxs[lr][c4] = v;
  }
  __syncthreads();
  int q = t & 31;
  int rg = t >> 5;
  float acc[8][4];
  #pragma unroll
  for (int r = 0; r < 8; ++r)
    #pragma unroll
    for (int j = 0; j < 4; ++j) acc[r][j] = 0.f;
  #pragma unroll 4
  for (int fc = 0; fc < 16; ++fc) {
    float4 b[4];
    #pragma unroll
    for (int j = 0; j < 4; ++j) b[j] = *(const float4*)&Bs[4 * q + j][fc * 4];
    #pragma unroll
    for (int r = 0; r < 8; ++r) {
      float4 p = *(const float4*)&pxs[rg * 8 + r][fc * 4];
      #pragma unroll
      for (int j = 0; j < 4; ++j)
        acc[r][j] += p.x * b[j].x + p.y * b[j].y + p.z * b[j].z + p.w * b[j].w;
    }
  }
  #pragma unroll
  for (int r = 0; r < 8; ++r) {
    int grow = r0 + rg * 8 + r;
    if (grow >= NROWS) continue;
    if (q < 16) {
      float4 v = make_float4(acc[r][0], acc[r][1], acc[r][2], acc[r][3]);
      *(float4*)(yi + (size_t)grow * 64 + q * 4) = v;
    } else {
      ushort4 h;
      h.x = f2bf(acc[r][0]); h.y = f2bf(acc[r][1]);
      h.z = f2bf(acc[r][2]); h.w = f2bf(acc[r][3]);
      *(ushort4*)(yjb + (size_t)grow * 64 + (q - 16) * 4) = h;
    }
  }
}

// --- CSR build step 1: histogram of idx_i ---
__global__ __launch_bounds__(256) void hist_kernel(
    const int* __restrict__ idx_i, int* __restrict__ cnt) {
  int e = blockIdx.x * 256 + threadIdx.x;
  if (e < N_EDGES) atomicAdd(&cnt[idx_i[e]], 1);
}

// --- CSR build step 2: exclusive scan, 8 elems/thread (single block) ---
__global__ __launch_bounds__(1024) void scan_kernel(
    const int* __restrict__ cnt, int* __restrict__ offs, int* __restrict__ cursor) {
  __shared__ int wsum[16];
  __shared__ int s_carry;
  int t = threadIdx.x, w = t >> 6, l = t & 63;
  if (t == 0) { s_carry = 0; offs[0] = 0; }
  __syncthreads();
  for (int base = 0; base < N_NODES; base += 8192) {
    int i0 = base + t * 8;
    int x[8];
    if (i0 + 7 < N_NODES) {
      int4 a = *(const int4*)(cnt + i0);
      int4 b = *(const int4*)(cnt + i0 + 4);
      x[0] = a.x; x[1] = a.y; x[2] = a.z; x[3] = a.w;
      x[4] = b.x; x[5] = b.y; x[6] = b.z; x[7] = b.w;
    } else {
      #pragma unroll
      for (int k = 0; k < 8; ++k) x[k] = (i0 + k < N_NODES) ? cnt[i0 + k] : 0;
    }
    int incl[8];
    int p = 0;
    #pragma unroll
    for (int k = 0; k < 8; ++k) { p += x[k]; incl[k] = p; }
    int tsum = p;
    int ts = tsum;
    #pragma unroll
    for (int off = 1; off < 64; off <<= 1) {
      int y = __shfl_up(ts, off, 64);
      if (l >= off) ts += y;
    }
    if (l == 63) wsum[w] = ts;
    __syncthreads();
    if (t < 16) {
      int ws_ = wsum[t];
      int si = ws_;
      #pragma unroll
      for (int off = 1; off < 16; off <<= 1) {
        int y = __shfl_up(si, off, 16);
        if (t >= off) si += y;
      }
      wsum[t] = si - ws_;          // exclusive wave base
    }
    __syncthreads();
    int basev = s_carry + wsum[w] + (ts - tsum);
    #pragma unroll
    for (int k = 0; k < 8; ++k) {
      int i = i0 + k;
      if (i < N_NODES) {
        int it = basev + incl[k];
        offs[i + 1] = it;
        cursor[i] = it - x[k];
      }
    }
    __syncthreads();
    if (t == 1023) s_carry = basev + tsum;
    __syncthreads();
  }
}

// --- CSR build step 3: scatter edge id + permuted idx_j + permuted diff ---
__global__ __launch_bounds__(256) void scatter_kernel(
    const int* __restrict__ idx_i, const int* __restrict__ idx_j,
    const float* __restrict__ diff, int* __restrict__ cursor,
    int* __restrict__ perm, int* __restrict__ pnj, float* __restrict__ pdiff) {
  int e = blockIdx.x * 256 + threadIdx.x;
  if (e < N_EDGES) {
    int pos = atomicAdd(&cursor[idx_i[e]], 1);
    perm[pos] = e;
    pnj[pos] = idx_j[e];
    pdiff[pos * 3 + 0] = diff[e * 3 + 0];
    pdiff[pos * 3 + 1] = diff[e * 3 + 1];
    pdiff[pos * 3 + 2] = diff[e * 3 + 2];
  }
}

// --- main: per (node,v) wave; linear metadata, single random gather ---
__global__ __launch_bounds__(192) void node_edge_kernel(
    const int* __restrict__ offs, const int* __restrict__ perm,
    const int* __restrict__ pnj, const float* __restrict__ pdiff,
    const float* __restrict__ yi, const unsigned short* __restrict__ yjb,
    float* __restrict__ ix_out, float* __restrict__ px_out) {
  int n = blockIdx.x;
  int v = threadIdx.x >> 6;          // 0..2 (one wave per v)
  int lane = threadIdx.x & 63;
  int s = lane >> 4;                 // edge slot 0..3
  int fq = (lane & 15) * 4;          // feature quad
  int start = offs[n], end = offs[n + 1];
  const float4 yiv = *(const float4*)(yi + ((size_t)n * 3 + v) * 64 + fq);
  float4 acc = make_float4(0.f, 0.f, 0.f, 0.f);
  float sum_d = 0.f;

  for (int p = start + s; p < end; p += 4) {
    int e   = perm[p];                       // linear (L1/L2)
    int nj  = pnj[p];                        // linear (L1/L2)
    float d = pdiff[p * 3 + v];              // linear-ish
    const ushort4 yw = *(const ushort4*)(yjb + ((size_t)nj * 3 + v) * 64 + fq);
    float4 yjv = make_float4(bf2f(yw.x), bf2f(yw.y), bf2f(yw.z), bf2f(yw.w));
    acc.x += d * yjv.x; acc.y += d * yjv.y;
    acc.z += d * yjv.z; acc.w += d * yjv.w;
    sum_d += d;
    floatx4 r;
    r.x = d * (yiv.x + yjv.x); r.y = d * (yiv.y + yjv.y);
    r.z = d * (yiv.z + yjv.z); r.w = d * (yiv.w + yjv.w);
    __builtin_nontemporal_store(r, (floatx4*)(ix_out + ((size_t)e * 3 + v) * 64 + fq));
  }
  // reduce over the 4 edge slots (lanes xor 16, 32)
  #pragma unroll
  for (int mm = 16; mm < 64; mm <<= 1) {
    acc.x += __shfl_xor(acc.x, mm, 64);
    acc.y += __shfl_xor(acc.y, mm, 64);
    acc.z += __shfl_xor(acc.z, mm, 64);
    acc.w += __shfl_xor(acc.w, mm, 64);
    sum_d += __shfl_xor(sum_d, mm, 64);
  }
  if (s == 0) {
    float4 o = make_float4(yiv.x * sum_d + acc.x, yiv.y * sum_d + acc.y,
                           yiv.z * sum_d + acc.z, yiv.w * sum_d + acc.w);
    *(float4*)(px_out + ((size_t)n * 3 + v) * 64 + fq) = o;
  }
}

extern "C" void kernel_launch(void* const* d_in, const int* in_sizes, int n_in,
                              void* d_out, int out_size, void* d_ws, size_t ws_size,
                              hipStream_t stream) {
  const int*   idx_i = (const int*)d_in[0];
  const int*   idx_j = (const int*)d_in[1];
  const float* px    = (const float*)d_in[2];
  const float* diff  = (const float*)d_in[3];
  const float* W_pp  = (const float*)d_in[4];
  const float* W_i   = (const float*)d_in[5];
  const float* W_j   = (const float*)d_in[6];
  const float* W_ii  = (const float*)d_in[7];

  float* px_out = (float*)d_out;              // [50000,3,64]
  float* ix_out = (float*)d_out + NPX;        // [800000,3,64]

  float* ws = (float*)d_ws;
  float* yi = ws;                              // [150000,64] f32
  unsigned short* yjb = (unsigned short*)(yi + (size_t)NPX);   // [150000,64] bf16
  float* Ci = (float*)(yjb + (size_t)NPX);
  float* Cj = Ci + 4096;
  float* Bi = Cj + 4096;
  float* Bj = Bi + 4096;
  int* cnt    = (int*)(Bj + 4096);             // [50000]
  int* offs   = cnt + N_NODES;                 // [50001]
  int* cursor = offs + N_NODES + 1;            // [50000]
  int* perm   = cursor + N_NODES;              // [800000]
  int* pnj    = perm + N_EDGES;                // [800000]
  float* pdiff = (float*)(pnj + N_EDGES);      // [800000*3]

  (void)hipMemsetAsync(cnt, 0, N_NODES * sizeof(int), stream);

  // Bi = W_ii @ W_i @ W_pp ; Bj = W_ii @ W_j @ W_pp
  mm64_pair<<<2, 256, 0, stream>>>(W_ii, W_i, Ci, W_ii, W_j, Cj);
  mm64_pair<<<2, 256, 0, stream>>>(Ci, W_pp, Bi, Cj, W_pp, Bj);

  node_mm<<<(NROWS + 63) / 64, 256, 0, stream>>>(px, Bi, Bj, yi, yjb);

  hist_kernel<<<(N_EDGES + 255) / 256, 256, 0, stream>>>(idx_i, cnt);
  scan_kernel<<<1, 1024, 0, stream>>>(cnt, offs, cursor);
  scatter_kernel<<<(N_EDGES + 255) / 256, 256, 0, stream>>>(
      idx_i, idx_j, diff, cursor, perm, pnj, pdiff);

  node_edge_kernel<<<N_NODES, 192, 0, stream>>>(offs, perm, pnj, pdiff,
                                                yi, yjb, ix_out, px_out);
}